// Round 4
// baseline (720.607 us; speedup 1.0000x reference)
//
#include <hip/hip_runtime.h>
#include <hip/hip_bf16.h>

#define B_ 32
#define S_ 2048
#define D_ 1024
#define U_ 1024
#define M_ (B_ * S_)

typedef __attribute__((ext_vector_type(8))) short bf16x8;
typedef __attribute__((ext_vector_type(4))) float f32x4;

__device__ __forceinline__ unsigned short f2bf(float x) {
  unsigned int u = __float_as_uint(x);
  unsigned int r = (u + 0x7FFFu + ((u >> 16) & 1u)) >> 16;  // RNE
  return (unsigned short)r;
}

__device__ __forceinline__ void gload_lds16(const void* g, void* l) {
  __builtin_amdgcn_global_load_lds(
      (const __attribute__((address_space(1))) unsigned int*)g,
      (__attribute__((address_space(3))) unsigned int*)l, 16, 0, 0);
}

// ---- K1: values fp32 -> bf16 (makes the GEMM A-operand L3-resident: 134MB) ----
__global__ void k_cvt(const float* __restrict__ v, unsigned short* __restrict__ o, int n8) {
  int i = blockIdx.x * blockDim.x + threadIdx.x;
  int stride = gridDim.x * blockDim.x;
  for (; i < n8; i += stride) {
    const float4* p = (const float4*)(v + (size_t)i * 8);
    float4 a = p[0];
    float4 b = p[1];
    uint4 r;
    r.x = (unsigned)f2bf(a.x) | ((unsigned)f2bf(a.y) << 16);
    r.y = (unsigned)f2bf(a.z) | ((unsigned)f2bf(a.w) << 16);
    r.z = (unsigned)f2bf(b.x) | ((unsigned)f2bf(b.y) << 16);
    r.w = (unsigned)f2bf(b.z) | ((unsigned)f2bf(b.w) << 16);
    ((uint4*)o)[i] = r;
  }
}

// ---- K2: W1 [D][U] fp32 -> W1T [U][D] bf16 (B^T layout for linear-LDS staging) ----
__global__ void k_transpose(const float* __restrict__ w1, unsigned short* __restrict__ w1t) {
  __shared__ float tile[32][33];
  int u0 = blockIdx.x * 32, d0 = blockIdx.y * 32;
  int tx = threadIdx.x & 31, ty = threadIdx.x >> 5;  // 32 x 8
  #pragma unroll
  for (int i = 0; i < 32; i += 8)
    tile[ty + i][tx] = w1[(size_t)(d0 + ty + i) * U_ + u0 + tx];
  __syncthreads();
  #pragma unroll
  for (int i = 0; i < 32; i += 8)
    w1t[(size_t)(u0 + ty + i) * D_ + d0 + tx] = f2bf(tile[tx][ty + i]);
}

// ---- K3: q2[b][u] = query[b,:]. W2[:,u] + b1[u] + b2[u]  (b1 folded in; bv skipped: softmax-invariant) ----
__global__ void k_q(const float* __restrict__ query, const float* __restrict__ w2,
                    const float* __restrict__ b1, const float* __restrict__ b2,
                    float* __restrict__ q2) {
  int u = blockIdx.x * 256 + threadIdx.x;
  int b = blockIdx.y;
  const float* qr = query + b * D_;
  float acc = 0.f;
  #pragma unroll 8
  for (int d = 0; d < D_; ++d) acc = fmaf(qr[d], w2[(size_t)d * U_ + u], acc);
  q2[b * U_ + u] = acc + b1[u] + b2[u];
}

// ---- K4: fused GEMM + tanh + V-dot -> partial scores (m97 structure: 128x128x64, 4 waves 2x2) ----
#define BM 128
#define BN 128
#define BK 64

__launch_bounds__(256, 2)
__global__ void k_gemm_score(const unsigned short* __restrict__ A,   // [M][D] bf16
                             const unsigned short* __restrict__ Bt,  // [U][D] bf16
                             const float* __restrict__ q2,           // [B][U]
                             const float* __restrict__ V,            // [U]
                             float* __restrict__ scores)             // [M]
{
  __shared__ unsigned short As[BM * BK];  // [row][k] linear, 16 KB
  __shared__ unsigned short Bs[BN * BK];  // [u][k]  linear, 16 KB
  const int tid = threadIdx.x, wid = tid >> 6, lane = tid & 63;
  const int bn = blockIdx.x, bm = blockIdx.y;
  const int row0 = bm * BM, col0 = bn * BN;
  const int b_idx = row0 / S_;  // whole block inside one batch row (S%BM==0)

  // staging: wave w, call c -> region r = w*4+c (8 rows, 1KB); lane l -> row r*8 + (l>>3), k (l&7)*8
  const int srow = lane >> 3;
  const int skcol = (lane & 7) * 8;

  f32x4 acc[4][4];
  #pragma unroll
  for (int m = 0; m < 4; ++m)
    #pragma unroll
    for (int n = 0; n < 4; ++n) acc[m][n] = (f32x4){0.f, 0.f, 0.f, 0.f};

  const unsigned short* Ag = A + (size_t)row0 * D_;
  const unsigned short* Bg = Bt + (size_t)col0 * D_;
  const int am = (wid >> 1) * 64;
  const int an = (wid & 1) * 64;

  for (int kt = 0; kt < D_; kt += BK) {
    #pragma unroll
    for (int c = 0; c < 4; ++c) {
      const int r = wid * 4 + c;
      gload_lds16(Ag + (size_t)(r * 8 + srow) * D_ + kt + skcol, &As[r * 512]);
      gload_lds16(Bg + (size_t)(r * 8 + srow) * D_ + kt + skcol, &Bs[r * 512]);
    }
    __syncthreads();  // drains vmcnt
    #pragma unroll
    for (int ks = 0; ks < 2; ++ks) {
      bf16x8 af[4], bfr[4];
      const int kf = ks * 32 + (lane >> 4) * 8;
      #pragma unroll
      for (int m = 0; m < 4; ++m)
        af[m] = *(const bf16x8*)&As[(am + m * 16 + (lane & 15)) * BK + kf];
      #pragma unroll
      for (int n = 0; n < 4; ++n)
        bfr[n] = *(const bf16x8*)&Bs[(an + n * 16 + (lane & 15)) * BK + kf];
      #pragma unroll
      for (int m = 0; m < 4; ++m)
        #pragma unroll
        for (int n = 0; n < 4; ++n)
          acc[m][n] = __builtin_amdgcn_mfma_f32_16x16x32_bf16(af[m], bfr[n], acc[m][n], 0, 0, 0);
    }
    __syncthreads();
  }

  // epilogue: score_partial[row] = sum_u tanh(kv + q2[b][u]) * V[u] over this block's 128 u's
  // C/D layout (verified m89/m91): col = lane&15, row = (lane>>4)*4 + reg
  const int colb = lane & 15, rowg = lane >> 4;
  #pragma unroll
  for (int m = 0; m < 4; ++m) {
    float s0 = 0.f, s1 = 0.f, s2 = 0.f, s3 = 0.f;
    #pragma unroll
    for (int n = 0; n < 4; ++n) {
      const int u = col0 + an + n * 16 + colb;
      const float qv = q2[b_idx * U_ + u];
      const float vv = V[u];
      s0 += tanhf(acc[m][n][0] + qv) * vv;
      s1 += tanhf(acc[m][n][1] + qv) * vv;
      s2 += tanhf(acc[m][n][2] + qv) * vv;
      s3 += tanhf(acc[m][n][3] + qv) * vv;
    }
    #pragma unroll
    for (int off = 1; off < 16; off <<= 1) {
      s0 += __shfl_xor(s0, off);
      s1 += __shfl_xor(s1, off);
      s2 += __shfl_xor(s2, off);
      s3 += __shfl_xor(s3, off);
    }
    if (colb == 0) {
      const int r = row0 + am + m * 16 + rowg * 4;
      atomicAdd(&scores[r + 0], s0);
      atomicAdd(&scores[r + 1], s1);
      atomicAdd(&scores[r + 2], s2);
      atomicAdd(&scores[r + 3], s3);
    }
  }
}

// ---- K5: softmax over S per batch; writes attention_weights output ----
__global__ void k_softmax(const float* __restrict__ scores, float* __restrict__ attw) {
  const int b = blockIdx.x;
  const float* s = scores + b * S_;
  const int tid = threadIdx.x;
  __shared__ float wred[4], wsum[4];
  float v[8];
  float lmax = -1e30f;
  #pragma unroll
  for (int i = 0; i < 8; ++i) {
    v[i] = s[tid + i * 256];
    lmax = fmaxf(lmax, v[i]);
  }
  #pragma unroll
  for (int off = 32; off > 0; off >>= 1) lmax = fmaxf(lmax, __shfl_xor(lmax, off));
  if ((tid & 63) == 0) wred[tid >> 6] = lmax;
  __syncthreads();
  const float bmax = fmaxf(fmaxf(wred[0], wred[1]), fmaxf(wred[2], wred[3]));
  float lsum = 0.f;
  #pragma unroll
  for (int i = 0; i < 8; ++i) {
    v[i] = expf(v[i] - bmax);
    lsum += v[i];
  }
  #pragma unroll
  for (int off = 32; off > 0; off >>= 1) lsum += __shfl_xor(lsum, off);
  if ((tid & 63) == 0) wsum[tid >> 6] = lsum;
  __syncthreads();
  const float inv = 1.f / (wsum[0] + wsum[1] + wsum[2] + wsum[3]);
  #pragma unroll
  for (int i = 0; i < 8; ++i) attw[b * S_ + tid + i * 256] = v[i] * inv;
}

// ---- K6: context[b][d] = sum_s w[b][s] * values[b][s][d] (fp32 pass, memory-bound) ----
__global__ void k_context(const float* __restrict__ values, const float* __restrict__ attw,
                          float* __restrict__ ctx) {
  const int b = blockIdx.y;
  const int s0 = blockIdx.x * (S_ / 16);
  const int t = threadIdx.x;
  const float* vb = values + (size_t)b * S_ * D_;
  float4 acc = make_float4(0.f, 0.f, 0.f, 0.f);
  for (int s = s0; s < s0 + S_ / 16; ++s) {
    const float w = attw[b * S_ + s];
    const float4 v = *(const float4*)(vb + (size_t)s * D_ + t * 4);
    acc.x = fmaf(w, v.x, acc.x);
    acc.y = fmaf(w, v.y, acc.y);
    acc.z = fmaf(w, v.z, acc.z);
    acc.w = fmaf(w, v.w, acc.w);
  }
  float* c = ctx + b * D_ + t * 4;
  atomicAdd(c + 0, acc.x);
  atomicAdd(c + 1, acc.y);
  atomicAdd(c + 2, acc.z);
  atomicAdd(c + 3, acc.w);
}

extern "C" void kernel_launch(void* const* d_in, const int* in_sizes, int n_in,
                              void* d_out, int out_size, void* d_ws, size_t ws_size,
                              hipStream_t stream) {
  const float* query = (const float*)d_in[0];
  const float* values = (const float*)d_in[1];
  const float* W1 = (const float*)d_in[2];
  const float* b1 = (const float*)d_in[3];
  const float* W2 = (const float*)d_in[4];
  const float* b2 = (const float*)d_in[5];
  const float* V = (const float*)d_in[6];
  // d_in[7] = bv: additive constant before softmax -> softmax-invariant, unused.

  float* out = (float*)d_out;
  float* ctx = out;                 // [B, D]
  float* attw = out + B_ * D_;      // [B, S, 1]

  char* ws = (char*)d_ws;
  const size_t VBF_BYTES = (size_t)M_ * D_ * 2;
  const size_t W1T_BYTES = (size_t)U_ * D_ * 2;
  const size_t Q2_BYTES = (size_t)B_ * U_ * 4;
  unsigned short* vbf = (unsigned short*)ws;
  unsigned short* w1t = (unsigned short*)(ws + VBF_BYTES);
  float* q2 = (float*)(ws + VBF_BYTES + W1T_BYTES);
  float* scores = (float*)(ws + VBF_BYTES + W1T_BYTES + Q2_BYTES);

  hipMemsetAsync(scores, 0, (size_t)M_ * 4, stream);
  hipMemsetAsync(ctx, 0, (size_t)B_ * D_ * 4, stream);

  k_cvt<<<2048, 256, 0, stream>>>(values, vbf, M_ * D_ / 8);
  k_transpose<<<dim3(U_ / 32, D_ / 32), 256, 0, stream>>>(W1, w1t);
  k_q<<<dim3(U_ / 256, B_), 256, 0, stream>>>(query, W2, b1, b2, q2);
  k_gemm_score<<<dim3(U_ / BN, M_ / BM), 256, 0, stream>>>(vbf, w1t, q2, V, scores);
  k_softmax<<<B_, 256, 0, stream>>>(scores, attw);
  k_context<<<dim3(16, B_), 256, 0, stream>>>(values, attw, ctx);
}

// Round 5
// 642.754 us; speedup vs baseline: 1.1211x; 1.1211x over previous
//
#include <hip/hip_runtime.h>
#include <hip/hip_bf16.h>

#define B_ 32
#define S_ 2048
#define D_ 1024
#define U_ 1024
#define M_ (B_ * S_)

typedef __attribute__((ext_vector_type(8))) short bf16x8;
typedef __attribute__((ext_vector_type(4))) float f32x4;

__device__ __forceinline__ unsigned short f2bf(float x) {
  unsigned int u = __float_as_uint(x);
  unsigned int r = (u + 0x7FFFu + ((u >> 16) & 1u)) >> 16;  // RNE
  return (unsigned short)r;
}

// tanh(x) = 1 - 2/(exp(2x)+1); v_exp_f32 + v_rcp_f32, ~6 VALU ops vs ~40 for libm tanhf.
// Limits: x->+inf: exp2->inf, rcp->0 => 1.  x->-inf: exp2->0 => -1.  err ~1e-7 << bf16 noise.
__device__ __forceinline__ float fast_tanh(float x) {
  float e = __builtin_amdgcn_exp2f(x * 2.88539008177793f);  // 2*log2(e)
  return 1.0f - 2.0f * __builtin_amdgcn_rcpf(e + 1.0f);
}

__device__ __forceinline__ void gload_lds16(const void* g, void* l) {
  __builtin_amdgcn_global_load_lds(
      (const __attribute__((address_space(1))) unsigned int*)g,
      (__attribute__((address_space(3))) unsigned int*)l, 16, 0, 0);
}

// ---- K1: values fp32 -> bf16 (makes the GEMM A-operand L3-resident: 134MB) ----
__global__ void k_cvt(const float* __restrict__ v, unsigned short* __restrict__ o, int n8) {
  int i = blockIdx.x * blockDim.x + threadIdx.x;
  int stride = gridDim.x * blockDim.x;
  for (; i < n8; i += stride) {
    const float4* p = (const float4*)(v + (size_t)i * 8);
    float4 a = p[0];
    float4 b = p[1];
    uint4 r;
    r.x = (unsigned)f2bf(a.x) | ((unsigned)f2bf(a.y) << 16);
    r.y = (unsigned)f2bf(a.z) | ((unsigned)f2bf(a.w) << 16);
    r.z = (unsigned)f2bf(b.x) | ((unsigned)f2bf(b.y) << 16);
    r.w = (unsigned)f2bf(b.z) | ((unsigned)f2bf(b.w) << 16);
    ((uint4*)o)[i] = r;
  }
}

// ---- K2: W1 [D][U] fp32 -> W1T [U][D] bf16 (B^T layout for linear-LDS staging) ----
__global__ void k_transpose(const float* __restrict__ w1, unsigned short* __restrict__ w1t) {
  __shared__ float tile[32][33];
  int u0 = blockIdx.x * 32, d0 = blockIdx.y * 32;
  int tx = threadIdx.x & 31, ty = threadIdx.x >> 5;  // 32 x 8
  #pragma unroll
  for (int i = 0; i < 32; i += 8)
    tile[ty + i][tx] = w1[(size_t)(d0 + ty + i) * U_ + u0 + tx];
  __syncthreads();
  #pragma unroll
  for (int i = 0; i < 32; i += 8)
    w1t[(size_t)(u0 + ty + i) * D_ + d0 + tx] = f2bf(tile[tx][ty + i]);
}

// ---- K3: q2[b][u] = query[b,:].W2[:,u] + b1[u] + b2[u]  (1024 blocks: 32u x 8 d-groups + LDS reduce) ----
__global__ void k_q(const float* __restrict__ query, const float* __restrict__ w2,
                    const float* __restrict__ b1, const float* __restrict__ b2,
                    float* __restrict__ q2) {
  const int ul = threadIdx.x & 31, dg = threadIdx.x >> 5;
  const int u = blockIdx.x * 32 + ul;
  const int b = blockIdx.y;
  const float* qr = query + b * D_;
  float acc = 0.f;
  const int d0 = dg * 128;
  #pragma unroll 8
  for (int d = d0; d < d0 + 128; ++d) acc = fmaf(qr[d], w2[(size_t)d * U_ + u], acc);
  __shared__ float red[8][32];
  red[dg][ul] = acc;
  __syncthreads();
  if (dg == 0) {
    float s = red[0][ul] + red[1][ul] + red[2][ul] + red[3][ul] +
              red[4][ul] + red[5][ul] + red[6][ul] + red[7][ul];
    q2[b * U_ + u] = s + b1[u] + b2[u];
  }
}

// ---- K4: fused GEMM + tanh + V-dot -> partial scores (m97 structure: 128x128x64, 4 waves 2x2) ----
#define BM 128
#define BN 128
#define BK 64

__launch_bounds__(256, 2)
__global__ void k_gemm_score(const unsigned short* __restrict__ A,   // [M][D] bf16
                             const unsigned short* __restrict__ Bt,  // [U][D] bf16
                             const float* __restrict__ q2,           // [B][U]
                             const float* __restrict__ V,            // [U]
                             float* __restrict__ scores)             // [M]
{
  __shared__ unsigned short As[BM * BK];  // [row][k] linear, 16 KB
  __shared__ unsigned short Bs[BN * BK];  // [u][k]  linear, 16 KB
  const int tid = threadIdx.x, wid = tid >> 6, lane = tid & 63;

  // XCD-chunked swizzle (T1): hw id L -> work (bm,bn) with all 8 n-tiles of an
  // m-panel on ONE XCD (L = m%8 + 8n + 64*(m/8); XCD = L%8 = m%8), temporally
  // adjacent so the 256KB A-panel is read once into that XCD's L2 and re-hit 7x.
  // Bijective: 4096 blocks, 4096 = 8*512. (FETCH predicted 532MB -> ~180MB)
  const int L = blockIdx.x + blockIdx.y * 8;
  const int bn = (L >> 3) & 7;
  const int bm = (L & 7) + ((L >> 6) << 3);
  const int row0 = bm * BM, col0 = bn * BN;
  const int b_idx = row0 / S_;  // whole block inside one batch row (S%BM==0)

  // staging: wave w, call c -> region r = w*4+c (8 rows, 1KB); lane l -> row r*8 + (l>>3), k (l&7)*8
  const int srow = lane >> 3;
  const int skcol = (lane & 7) * 8;

  f32x4 acc[4][4];
  #pragma unroll
  for (int m = 0; m < 4; ++m)
    #pragma unroll
    for (int n = 0; n < 4; ++n) acc[m][n] = (f32x4){0.f, 0.f, 0.f, 0.f};

  const unsigned short* Ag = A + (size_t)row0 * D_;
  const unsigned short* Bg = Bt + (size_t)col0 * D_;
  const int am = (wid >> 1) * 64;
  const int an = (wid & 1) * 64;

  for (int kt = 0; kt < D_; kt += BK) {
    #pragma unroll
    for (int c = 0; c < 4; ++c) {
      const int r = wid * 4 + c;
      gload_lds16(Ag + (size_t)(r * 8 + srow) * D_ + kt + skcol, &As[r * 512]);
      gload_lds16(Bg + (size_t)(r * 8 + srow) * D_ + kt + skcol, &Bs[r * 512]);
    }
    __syncthreads();  // drains vmcnt
    #pragma unroll
    for (int ks = 0; ks < 2; ++ks) {
      bf16x8 af[4], bfr[4];
      const int kf = ks * 32 + (lane >> 4) * 8;
      #pragma unroll
      for (int m = 0; m < 4; ++m)
        af[m] = *(const bf16x8*)&As[(am + m * 16 + (lane & 15)) * BK + kf];
      #pragma unroll
      for (int n = 0; n < 4; ++n)
        bfr[n] = *(const bf16x8*)&Bs[(an + n * 16 + (lane & 15)) * BK + kf];
      #pragma unroll
      for (int m = 0; m < 4; ++m)
        #pragma unroll
        for (int n = 0; n < 4; ++n)
          acc[m][n] = __builtin_amdgcn_mfma_f32_16x16x32_bf16(af[m], bfr[n], acc[m][n], 0, 0, 0);
    }
    __syncthreads();
  }

  // epilogue: score_partial[row] = sum_u tanh(kv + q2[b][u]) * V[u] over this block's 128 u's
  // C/D layout (verified m89/m91): col = lane&15, row = (lane>>4)*4 + reg
  const int colb = lane & 15, rowg = lane >> 4;
  #pragma unroll
  for (int m = 0; m < 4; ++m) {
    float s0 = 0.f, s1 = 0.f, s2 = 0.f, s3 = 0.f;
    #pragma unroll
    for (int n = 0; n < 4; ++n) {
      const int u = col0 + an + n * 16 + colb;
      const float qv = q2[b_idx * U_ + u];
      const float vv = V[u];
      s0 += fast_tanh(acc[m][n][0] + qv) * vv;
      s1 += fast_tanh(acc[m][n][1] + qv) * vv;
      s2 += fast_tanh(acc[m][n][2] + qv) * vv;
      s3 += fast_tanh(acc[m][n][3] + qv) * vv;
    }
    #pragma unroll
    for (int off = 1; off < 16; off <<= 1) {
      s0 += __shfl_xor(s0, off);
      s1 += __shfl_xor(s1, off);
      s2 += __shfl_xor(s2, off);
      s3 += __shfl_xor(s3, off);
    }
    if (colb == 0) {
      const int r = row0 + am + m * 16 + rowg * 4;
      atomicAdd(&scores[r + 0], s0);
      atomicAdd(&scores[r + 1], s1);
      atomicAdd(&scores[r + 2], s2);
      atomicAdd(&scores[r + 3], s3);
    }
  }
}

// ---- K5: softmax over S per batch; writes attention_weights output ----
__global__ void k_softmax(const float* __restrict__ scores, float* __restrict__ attw) {
  const int b = blockIdx.x;
  const float* s = scores + b * S_;
  const int tid = threadIdx.x;
  __shared__ float wred[4], wsum[4];
  float v[8];
  float lmax = -1e30f;
  #pragma unroll
  for (int i = 0; i < 8; ++i) {
    v[i] = s[tid + i * 256];
    lmax = fmaxf(lmax, v[i]);
  }
  #pragma unroll
  for (int off = 32; off > 0; off >>= 1) lmax = fmaxf(lmax, __shfl_xor(lmax, off));
  if ((tid & 63) == 0) wred[tid >> 6] = lmax;
  __syncthreads();
  const float bmax = fmaxf(fmaxf(wred[0], wred[1]), fmaxf(wred[2], wred[3]));
  float lsum = 0.f;
  #pragma unroll
  for (int i = 0; i < 8; ++i) {
    v[i] = expf(v[i] - bmax);
    lsum += v[i];
  }
  #pragma unroll
  for (int off = 32; off > 0; off >>= 1) lsum += __shfl_xor(lsum, off);
  if ((tid & 63) == 0) wsum[tid >> 6] = lsum;
  __syncthreads();
  const float inv = 1.f / (wsum[0] + wsum[1] + wsum[2] + wsum[3]);
  #pragma unroll
  for (int i = 0; i < 8; ++i) attw[b * S_ + tid + i * 256] = v[i] * inv;
}

// ---- K6: context[b][d] = sum_s w[b][s] * values[b][s][d] (fp32 pass, memory-bound) ----
__global__ void k_context(const float* __restrict__ values, const float* __restrict__ attw,
                          float* __restrict__ ctx) {
  const int b = blockIdx.y;
  const int s0 = blockIdx.x * (S_ / 16);
  const int t = threadIdx.x;
  const float* vb = values + (size_t)b * S_ * D_;
  float4 acc = make_float4(0.f, 0.f, 0.f, 0.f);
  for (int s = s0; s < s0 + S_ / 16; ++s) {
    const float w = attw[b * S_ + s];
    const float4 v = *(const float4*)(vb + (size_t)s * D_ + t * 4);
    acc.x = fmaf(w, v.x, acc.x);
    acc.y = fmaf(w, v.y, acc.y);
    acc.z = fmaf(w, v.z, acc.z);
    acc.w = fmaf(w, v.w, acc.w);
  }
  float* c = ctx + b * D_ + t * 4;
  atomicAdd(c + 0, acc.x);
  atomicAdd(c + 1, acc.y);
  atomicAdd(c + 2, acc.z);
  atomicAdd(c + 3, acc.w);
}

extern "C" void kernel_launch(void* const* d_in, const int* in_sizes, int n_in,
                              void* d_out, int out_size, void* d_ws, size_t ws_size,
                              hipStream_t stream) {
  const float* query = (const float*)d_in[0];
  const float* values = (const float*)d_in[1];
  const float* W1 = (const float*)d_in[2];
  const float* b1 = (const float*)d_in[3];
  const float* W2 = (const float*)d_in[4];
  const float* b2 = (const float*)d_in[5];
  const float* V = (const float*)d_in[6];
  // d_in[7] = bv: additive constant before softmax -> softmax-invariant, unused.

  float* out = (float*)d_out;
  float* ctx = out;                 // [B, D]
  float* attw = out + B_ * D_;      // [B, S, 1]

  char* ws = (char*)d_ws;
  const size_t VBF_BYTES = (size_t)M_ * D_ * 2;
  const size_t W1T_BYTES = (size_t)U_ * D_ * 2;
  const size_t Q2_BYTES = (size_t)B_ * U_ * 4;
  unsigned short* vbf = (unsigned short*)ws;
  unsigned short* w1t = (unsigned short*)(ws + VBF_BYTES);
  float* q2 = (float*)(ws + VBF_BYTES + W1T_BYTES);
  float* scores = (float*)(ws + VBF_BYTES + W1T_BYTES + Q2_BYTES);

  hipMemsetAsync(scores, 0, (size_t)M_ * 4, stream);
  hipMemsetAsync(ctx, 0, (size_t)B_ * D_ * 4, stream);

  k_cvt<<<2048, 256, 0, stream>>>(values, vbf, M_ * D_ / 8);
  k_transpose<<<dim3(U_ / 32, D_ / 32), 256, 0, stream>>>(W1, w1t);
  k_q<<<dim3(U_ / 32, B_), 256, 0, stream>>>(query, W2, b1, b2, q2);
  k_gemm_score<<<dim3(U_ / BN, M_ / BM), 256, 0, stream>>>(vbf, w1t, q2, V, scores);
  k_softmax<<<B_, 256, 0, stream>>>(scores, attw);
  k_context<<<dim3(16, B_), 256, 0, stream>>>(values, attw, ctx);
}